// Round 3
// baseline (419.010 us; speedup 1.0000x reference)
//
#include <hip/hip_runtime.h>

// ---------------------------------------------------------------------------
// MatryoshkaAttention on MI355X (gfx950), bf16 MFMA pipeline. Round 3.
//
// Changes vs R2:
//  - k_gemm_bt: XOR-swizzled LDS layout. global_load_lds forces dest =
//    wave-uniform base + lane*16B, so instead of padding we permute the
//    GLOBAL source column group per lane (j -> j ^ s(r), s(r)=(r&3)^((r>>2)&3))
//    and un-permute at the ds_read side (qd -> qd ^ s(row)). Fragment base
//    rows are multiples of 16, so s collapses to a per-lane constant ->
//    zero per-iter VALU. Breaks the 8-way bank conflict (2.94x) down to
//    2-way (free, m136).
// ---------------------------------------------------------------------------

typedef short bf16x8 __attribute__((ext_vector_type(8)));
typedef float floatx4 __attribute__((ext_vector_type(4)));

__device__ __forceinline__ unsigned short f2bf(float f) {
  unsigned u = __builtin_bit_cast(unsigned, f);
  u += 0x7fffu + ((u >> 16) & 1u);           // RNE
  return (unsigned short)(u >> 16);
}

__device__ __forceinline__ void gload_lds16(const unsigned short* g, unsigned short* l) {
  __builtin_amdgcn_global_load_lds((const __attribute__((address_space(1))) unsigned int*)g,
                                   (__attribute__((address_space(3))) unsigned int*)l, 16, 0, 0);
}

// ---------------- 1. x -> bf16 ----------------
__global__ void k_cvt_x(const float* __restrict__ in, unsigned short* __restrict__ out, int n4) {
  int i = blockIdx.x * blockDim.x + threadIdx.x;
  if (i >= n4) return;
  float4 v = ((const float4*)in)[i];
  union { unsigned short u[4]; uint2 v2; } o;
  o.u[0] = f2bf(v.x); o.u[1] = f2bf(v.y); o.u[2] = f2bf(v.z); o.u[3] = f2bf(v.w);
  ((uint2*)out)[i] = o.v2;
}

// ---------------- 2. Wc^T[n][k] = sum_r F[k, h*8+r] * P[h, r, d],  n = h*64+d
__global__ void k_build_wct(const float* __restrict__ F, const float* __restrict__ P,
                            float* __restrict__ out, int hi, int fstride) {
  int idx = blockIdx.x * blockDim.x + threadIdx.x;
  int k = idx % hi;
  int n = idx / hi;
  int h = n >> 6, d = n & 63;
  float s = 0.f;
#pragma unroll
  for (int r = 0; r < 8; ++r)
    s += F[(size_t)k * fstride + h * 8 + r] * P[h * 512 + r * 64 + d];
  out[(size_t)n * hi + k] = s;
}

// ---------------- 3a. W_QKV transpose+convert with corrections ----------------
__global__ void k_pack_qkv(const float* __restrict__ WQ, const float* __restrict__ WK,
                           const float* __restrict__ WV,
                           const float* __restrict__ cK0, const float* __restrict__ cV0,
                           const float* __restrict__ cK1, const float* __restrict__ cV1,
                           unsigned short* __restrict__ Wt) {
  __shared__ float tile[32][33];
  int k0 = blockIdx.x * 32, n0 = blockIdx.y * 32;
  int tx = threadIdx.x, ty = threadIdx.y;
  const float* src;
  int nboff;
  if (n0 < 1536)      { src = WQ; nboff = n0; }
  else if (n0 < 3072) { src = WK; nboff = n0 - 1536; }
  else                { src = WV; nboff = n0 - 3072; }
#pragma unroll
  for (int j = 0; j < 4; ++j) {
    int kk = ty + j * 8;
    tile[kk][tx] = src[(size_t)(k0 + kk) * 1536 + nboff + tx];
  }
  __syncthreads();
#pragma unroll
  for (int j = 0; j < 4; ++j) {
    int nn = ty + j * 8;
    int n = n0 + nn;
    int k = k0 + tx;
    float v = tile[tx][nn];
    if (n >= 1536) {
      int np = (n < 3072) ? (n - 1536) : (n - 3072);
      const float* cA = (n < 3072) ? cK0 : cV0;
      const float* cB = (n < 3072) ? cK1 : cV1;
      if (np < 256) {
        if (k >= 256) v += cA[(size_t)np * 1792 + (k - 256)];
      } else if (np < 768) {
        if (k >= 1024) v += cB[(size_t)(np - 256) * 1024 + (k - 1024)];
      }
    }
    Wt[(size_t)n * 2048 + k] = f2bf(v);
  }
}

// ---------------- 3b. W_O transpose+convert: Wt[n][k], n<2048, k<1536 -------
__global__ void k_pack_o(const float* __restrict__ WO, unsigned short* __restrict__ Wt) {
  __shared__ float tile[32][33];
  int k0 = blockIdx.x * 32, n0 = blockIdx.y * 32;
  int tx = threadIdx.x, ty = threadIdx.y;
#pragma unroll
  for (int j = 0; j < 4; ++j)
    tile[ty + j * 8][tx] = WO[(size_t)(k0 + ty + j * 8) * 2048 + n0 + tx];
  __syncthreads();
#pragma unroll
  for (int j = 0; j < 4; ++j) {
    int n = n0 + ty + j * 8, k = k0 + tx;
    Wt[(size_t)n * 1536 + k] = f2bf(tile[tx][ty + j * 8]);
  }
}

// ---------------- 4/6. GEMM (m97 + XOR swizzle): C = A[M][K] * Bt[N][K]^T ---
// 128x128 tile, 4 waves 2x2, BK=32, global_load_lds dwordx4, unpadded LDS
// with XOR-swizzled column groups (see header comment).
template <bool OUT_BF16>
__global__ __launch_bounds__(256) void k_gemm_bt(const unsigned short* __restrict__ A,
                                                 const unsigned short* __restrict__ Bt,
                                                 void* __restrict__ C, int M, int N, int K) {
  __shared__ unsigned short As[128 * 32];
  __shared__ unsigned short Bs[128 * 32];
  const int tid = threadIdx.x;
  const int wave = tid >> 6, lane = tid & 63;
  const int qd = lane >> 4, ln = lane & 15;
  const int bm = blockIdx.y * 128, bn = blockIdx.x * 128;
  const int wr = wave >> 1, wc = wave & 1;
  floatx4 acc[4][4];
#pragma unroll
  for (int i = 0; i < 4; ++i)
#pragma unroll
    for (int j = 0; j < 4; ++j) acc[i][j] = (floatx4){0.f, 0.f, 0.f, 0.f};
  // staging: wave w owns rows [w*32, w*32+32); one instr = 16 rows.
  // swizzle: lane's source col-group = (lane&3) ^ s(r), s(r)=(r&3)^((r>>2)&3);
  // r_local = lane>>2 (+16 for second gload: same s).
  const int srow = wave * 32 + (lane >> 2);
  const int sW = ((lane >> 2) & 3) ^ ((lane >> 4) & 3);
  const int scol = ((lane & 3) ^ sW) * 8;
  const unsigned short* gA = A + (size_t)(bm + srow) * K + scol;
  const unsigned short* gB = Bt + (size_t)(bn + srow) * K + scol;
  unsigned short* lA = As + wave * 1024;
  unsigned short* lB = Bs + wave * 1024;
  // reader: row read = base + ln (base % 16 == 0) -> s = (ln&3)^((ln>>2)&3)
  const int sR = (ln & 3) ^ ((ln >> 2) & 3);
  const int rcol = (qd ^ sR) * 8;
  for (int k0 = 0; k0 < K; k0 += 32) {
    __syncthreads();
    gload_lds16(gA + k0, lA);
    gload_lds16(gA + (size_t)16 * K + k0, lA + 512);
    gload_lds16(gB + k0, lB);
    gload_lds16(gB + (size_t)16 * K + k0, lB + 512);
    __syncthreads();
    bf16x8 af[4], bfr[4];
#pragma unroll
    for (int mi = 0; mi < 4; ++mi)
      af[mi] = *(const bf16x8*)(As + (wr * 64 + mi * 16 + ln) * 32 + rcol);
#pragma unroll
    for (int ni = 0; ni < 4; ++ni)
      bfr[ni] = *(const bf16x8*)(Bs + (wc * 64 + ni * 16 + ln) * 32 + rcol);
#pragma unroll
    for (int mi = 0; mi < 4; ++mi)
#pragma unroll
      for (int ni = 0; ni < 4; ++ni)
        acc[mi][ni] = __builtin_amdgcn_mfma_f32_16x16x32_bf16(af[mi], bfr[ni], acc[mi][ni], 0, 0, 0);
  }
#pragma unroll
  for (int mi = 0; mi < 4; ++mi)
#pragma unroll
    for (int r = 0; r < 4; ++r) {
      int row = bm + wr * 64 + mi * 16 + qd * 4 + r;
#pragma unroll
      for (int ni = 0; ni < 4; ++ni) {
        int col = bn + wc * 64 + ni * 16 + ln;
        if (OUT_BF16)
          ((unsigned short*)C)[(size_t)row * N + col] = f2bf(acc[mi][ni][r]);
        else
          ((float*)C)[(size_t)row * N + col] = acc[mi][ni][r];
      }
    }
}

// ---------------- 4b. V transpose: VT[b][d(1536)][T] from QKV cols 3072+ ----
__global__ void k_transpose_v(const unsigned short* __restrict__ QKV,
                              unsigned short* __restrict__ VT) {
  __shared__ unsigned short t[64 * 65];
  const int tt = blockIdx.x * 64, dt = blockIdx.y * 64, b = blockIdx.z;
  const int tid = threadIdx.x;
  const int r = tid >> 3, c0 = (tid & 7) * 8;
#pragma unroll
  for (int i = 0; i < 2; ++i) {
    int tok = r + i * 32;
    union { uint4 v; unsigned short u[8]; } vv;
    vv.v = *(const uint4*)(QKV + (size_t)(b * 1024 + tt + tok) * 4608 + 3072 + dt + c0);
#pragma unroll
    for (int j = 0; j < 8; ++j) t[tok * 65 + c0 + j] = vv.u[j];
  }
  __syncthreads();
#pragma unroll
  for (int i = 0; i < 2; ++i) {
    int d = r + i * 32;
    union { uint4 v; unsigned short u[8]; } vv;
#pragma unroll
    for (int j = 0; j < 8; ++j) vv.u[j] = t[(c0 + j) * 65 + d];
    *(uint4*)(VT + ((size_t)b * 1536 + dt + d) * 1024 + tt + c0) = vv.v;
  }
}

// ---------------- 5. causal flash attention (64-key tiles) ----------------
#define LDK 72   // shorts; 144B row stride -> 2-way bank aliasing (free)
#define LDP 72
__global__ __launch_bounds__(256) void k_attn(const unsigned short* __restrict__ QKV,
                                              const unsigned short* __restrict__ VT,
                                              unsigned short* __restrict__ Oout) {
  __shared__ unsigned short Ks[64 * LDK];
  __shared__ unsigned short VTs[64 * LDK];   // VTs[d][key]
  __shared__ unsigned short Pl[4][16 * LDP]; // wave-private P staging
  const int tid = threadIdx.x;
  const int wave = tid >> 6, lane = tid & 63;
  const int qd = lane >> 4, ln = lane & 15;
  const int qb = (int)gridDim.x - 1 - (int)blockIdx.x;   // big blocks first
  const int gh = blockIdx.y, b = blockIdx.z;
  const int T = 1024, LD = 4608;
  const size_t rowbase = (size_t)b * T * LD;
  const int qcol = 64 * gh, kcol = 1536 + 64 * gh;
  const int q0w = qb * 64 + wave * 16;
  const unsigned short* VTg = VT + ((size_t)b * 1536 + 64 * gh) * 1024;
  const float SCALE = 0.18033688f;  // 1/sqrt(64) * log2(e)

  bf16x8 aq0, aq1;
  {
    const unsigned short* qp = QKV + rowbase + (size_t)(q0w + ln) * LD + qcol;
    aq0 = *(const bf16x8*)(qp + qd * 8);
    aq1 = *(const bf16x8*)(qp + 32 + qd * 8);
  }
  floatx4 Oacc[4];
#pragma unroll
  for (int i = 0; i < 4; ++i) Oacc[i] = (floatx4){0.f, 0.f, 0.f, 0.f};
  float m_r[4], l_r[4];
#pragma unroll
  for (int r = 0; r < 4; ++r) { m_r[r] = -1e30f; l_r[r] = 0.f; }

  const int rr = tid >> 3, c0 = (tid & 7) * 8;
  for (int jt = 0; jt <= qb; ++jt) {
    const int jk = jt * 64;
    const bool diag = (jt == qb);
    __syncthreads();
#pragma unroll
    for (int i = 0; i < 2; ++i) {
      int kr = rr + i * 32;
      uint4 vk = *(const uint4*)(QKV + rowbase + (size_t)(jk + kr) * LD + kcol + c0);
      *(uint4*)(Ks + kr * LDK + c0) = vk;
      uint4 vv = *(const uint4*)(VTg + (size_t)kr * 1024 + jk + c0);
      *(uint4*)(VTs + kr * LDK + c0) = vv;
    }
    __syncthreads();

    floatx4 Sc[4];
#pragma unroll
    for (int h = 0; h < 4; ++h) {
      Sc[h] = (floatx4){0.f, 0.f, 0.f, 0.f};
      bf16x8 b0 = *(const bf16x8*)(Ks + (h * 16 + ln) * LDK + qd * 8);
      bf16x8 b1 = *(const bf16x8*)(Ks + (h * 16 + ln) * LDK + 32 + qd * 8);
      Sc[h] = __builtin_amdgcn_mfma_f32_16x16x32_bf16(aq0, b0, Sc[h], 0, 0, 0);
      Sc[h] = __builtin_amdgcn_mfma_f32_16x16x32_bf16(aq1, b1, Sc[h], 0, 0, 0);
    }
    float s[4][4];
    if (diag) {
#pragma unroll
      for (int h = 0; h < 4; ++h)
#pragma unroll
        for (int r = 0; r < 4; ++r) {
          int qrow = q0w + qd * 4 + r;
          int kidx = jk + h * 16 + ln;
          s[h][r] = (kidx <= qrow) ? Sc[h][r] * SCALE : -1e30f;
        }
    } else {
#pragma unroll
      for (int h = 0; h < 4; ++h)
#pragma unroll
        for (int r = 0; r < 4; ++r) s[h][r] = Sc[h][r] * SCALE;
    }
#pragma unroll
    for (int r = 0; r < 4; ++r) {
      float mx = fmaxf(fmaxf(s[0][r], s[1][r]), fmaxf(s[2][r], s[3][r]));
#pragma unroll
      for (int off = 1; off < 16; off <<= 1) mx = fmaxf(mx, __shfl_xor(mx, off, 64));
      float mn = fmaxf(m_r[r], mx);
      float al = __builtin_amdgcn_exp2f(m_r[r] - mn);
      float sum = 0.f;
#pragma unroll
      for (int h = 0; h < 4; ++h) {
        s[h][r] = __builtin_amdgcn_exp2f(s[h][r] - mn);
        sum += s[h][r];
      }
#pragma unroll
      for (int off = 1; off < 16; off <<= 1) sum += __shfl_xor(sum, off, 64);
      l_r[r] = l_r[r] * al + sum;
      m_r[r] = mn;
#pragma unroll
      for (int nc = 0; nc < 4; ++nc) Oacc[nc][r] *= al;
    }
    unsigned short* pw = Pl[wave];
#pragma unroll
    for (int r = 0; r < 4; ++r)
#pragma unroll
      for (int h = 0; h < 4; ++h)
        pw[(qd * 4 + r) * LDP + h * 16 + ln] = f2bf(s[h][r]);
    __asm__ volatile("s_waitcnt lgkmcnt(0)" ::: "memory");
    bf16x8 pa0 = *(const bf16x8*)(pw + ln * LDP + qd * 8);
    bf16x8 pa1 = *(const bf16x8*)(pw + ln * LDP + 32 + qd * 8);
#pragma unroll
    for (int nc = 0; nc < 4; ++nc) {
      bf16x8 bv0 = *(const bf16x8*)(VTs + (nc * 16 + ln) * LDK + qd * 8);
      bf16x8 bv1 = *(const bf16x8*)(VTs + (nc * 16 + ln) * LDK + 32 + qd * 8);
      Oacc[nc] = __builtin_amdgcn_mfma_f32_16x16x32_bf16(pa0, bv0, Oacc[nc], 0, 0, 0);
      Oacc[nc] = __builtin_amdgcn_mfma_f32_16x16x32_bf16(pa1, bv1, Oacc[nc], 0, 0, 0);
    }
  }
#pragma unroll
  for (int r = 0; r < 4; ++r) {
    float inv = 1.0f / l_r[r];
    size_t row = (size_t)b * T + q0w + qd * 4 + r;
#pragma unroll
    for (int nc = 0; nc < 4; ++nc)
      Oout[row * 1536 + 64 * gh + nc * 16 + ln] = f2bf(Oacc[nc][r] * inv);
  }
}

// ---------------------------------------------------------------------------
extern "C" void kernel_launch(void* const* d_in, const int* in_sizes, int n_in,
                              void* d_out, int out_size, void* d_ws, size_t ws_size,
                              hipStream_t stream) {
  (void)in_sizes; (void)n_in; (void)out_size; (void)ws_size;
  const float* x   = (const float*)d_in[0];
  const float* WQ  = (const float*)d_in[1];
  const float* WK  = (const float*)d_in[2];
  const float* WV  = (const float*)d_in[3];
  const float* WO  = (const float*)d_in[4];
  const float* FK0 = (const float*)d_in[5];
  const float* PK0 = (const float*)d_in[6];
  const float* FV0 = (const float*)d_in[7];
  const float* PV0 = (const float*)d_in[8];
  const float* FK1 = (const float*)d_in[9];
  const float* PK1 = (const float*)d_in[10];
  const float* FV1 = (const float*)d_in[11];
  const float* PV1 = (const float*)d_in[12];

  char* ws = (char*)d_ws;
  unsigned short* X16   = (unsigned short*)(ws + 0);          // 16 MB (dead after GEMM1)
  unsigned short* VTb   = X16;                                 // VT aliases X16
  unsigned short* WTQKV = (unsigned short*)(ws + 16777216);   // 18 MB
  unsigned short* QKV   = (unsigned short*)(ws + 35651584);   // 36 MB
  unsigned short* ATT   = (unsigned short*)(ws + 73400320);   // 12 MB
  unsigned short* WTO   = (unsigned short*)(ws + 85983232);   //  6 MB
  float* WCK0 = (float*)(ws + 92274688);
  float* WCV0 = (float*)(ws + 94109696);
  float* WCK1 = (float*)(ws + 95944704);
  float* WCV1 = (float*)(ws + 98041856);

  k_cvt_x<<<8192, 256, 0, stream>>>(x, X16, 2097152);
  k_build_wct<<<1792, 256, 0, stream>>>(FK0, PK0, WCK0, 1792, 32);
  k_build_wct<<<1792, 256, 0, stream>>>(FV0, PV0, WCV0, 1792, 32);
  k_build_wct<<<2048, 256, 0, stream>>>(FK1, PK1, WCK1, 1024, 64);
  k_build_wct<<<2048, 256, 0, stream>>>(FV1, PV1, WCV1, 1024, 64);
  k_pack_qkv<<<dim3(64, 144), dim3(32, 8), 0, stream>>>(WQ, WK, WV, WCK0, WCV0, WCK1, WCV1, WTQKV);
  k_pack_o<<<dim3(48, 64), dim3(32, 8), 0, stream>>>(WO, WTO);
  k_gemm_bt<true><<<dim3(36, 32), 256, 0, stream>>>(X16, WTQKV, QKV, 4096, 4608, 2048);
  k_transpose_v<<<dim3(16, 24, 4), 256, 0, stream>>>(QKV, VTb);
  k_attn<<<dim3(16, 24, 4), 256, 0, stream>>>(QKV, VTb, ATT);
  k_gemm_bt<false><<<dim3(16, 32), 256, 0, stream>>>(ATT, WTO, d_out, 4096, 2048, 1536);
}

// Round 4
// 365.636 us; speedup vs baseline: 1.1460x; 1.1460x over previous
//
#include <hip/hip_runtime.h>

// ---------------------------------------------------------------------------
// MatryoshkaAttention on MI355X (gfx950), bf16 MFMA pipeline. Round 4.
//
// Changes vs R3:
//  - k_gemm_bt: BK=64 (32KB LDS, halves barrier count; 8-group XOR swizzle).
//  - k_attn: no-max softmax. S^T = K*Q^T (C-layout puts 4 consecutive KEYS
//    per lane, q-row = ln). p = exp2(clamp(s,80)) unnormalized; l deferred
//    to a per-lane scalar partial (no per-tile shuffle reduces, no alpha
//    rescale of Oacc); P written as packed ds_write_b64; final l reduce =
//    2 shuffles once per kernel.
//  - 4x k_build_wct merged into one launch.
// ---------------------------------------------------------------------------

typedef short bf16x8 __attribute__((ext_vector_type(8)));
typedef float floatx4 __attribute__((ext_vector_type(4)));

__device__ __forceinline__ unsigned short f2bf(float f) {
  unsigned u = __builtin_bit_cast(unsigned, f);
  u += 0x7fffu + ((u >> 16) & 1u);           // RNE
  return (unsigned short)(u >> 16);
}

__device__ __forceinline__ void gload_lds16(const unsigned short* g, unsigned short* l) {
  __builtin_amdgcn_global_load_lds((const __attribute__((address_space(1))) unsigned int*)g,
                                   (__attribute__((address_space(3))) unsigned int*)l, 16, 0, 0);
}

// ---------------- 1. x -> bf16 ----------------
__global__ void k_cvt_x(const float* __restrict__ in, unsigned short* __restrict__ out, int n4) {
  int i = blockIdx.x * blockDim.x + threadIdx.x;
  if (i >= n4) return;
  float4 v = ((const float4*)in)[i];
  union { unsigned short u[4]; uint2 v2; } o;
  o.u[0] = f2bf(v.x); o.u[1] = f2bf(v.y); o.u[2] = f2bf(v.z); o.u[3] = f2bf(v.w);
  ((uint2*)out)[i] = o.v2;
}

// ---------------- 2. all four Wc^T builds in one launch ----------------
// Wc^T[n][k] = sum_r F[k, h*8+r] * P[h, r, d],  n = h*64+d
__global__ void k_build_all(const float* __restrict__ FK0, const float* __restrict__ PK0, float* __restrict__ WCK0,
                            const float* __restrict__ FV0, const float* __restrict__ PV0, float* __restrict__ WCV0,
                            const float* __restrict__ FK1, const float* __restrict__ PK1, float* __restrict__ WCK1,
                            const float* __restrict__ FV1, const float* __restrict__ PV1, float* __restrict__ WCV1) {
  int bid = blockIdx.x;
  const float *F, *P; float* O; int hi, fs, base;
  if (bid < 1792)      { F = FK0; P = PK0; O = WCK0; hi = 1792; fs = 32; base = 0; }
  else if (bid < 3584) { F = FV0; P = PV0; O = WCV0; hi = 1792; fs = 32; base = 1792; }
  else if (bid < 5632) { F = FK1; P = PK1; O = WCK1; hi = 1024; fs = 64; base = 3584; }
  else                 { F = FV1; P = PV1; O = WCV1; hi = 1024; fs = 64; base = 5632; }
  int idx = (bid - base) * 256 + threadIdx.x;
  int k = idx % hi;
  int n = idx / hi;
  int h = n >> 6, d = n & 63;
  float s = 0.f;
#pragma unroll
  for (int r = 0; r < 8; ++r)
    s += F[(size_t)k * fs + h * 8 + r] * P[h * 512 + r * 64 + d];
  O[(size_t)n * hi + k] = s;
}

// ---------------- 3a. W_QKV transpose+convert with corrections ----------------
__global__ void k_pack_qkv(const float* __restrict__ WQ, const float* __restrict__ WK,
                           const float* __restrict__ WV,
                           const float* __restrict__ cK0, const float* __restrict__ cV0,
                           const float* __restrict__ cK1, const float* __restrict__ cV1,
                           unsigned short* __restrict__ Wt) {
  __shared__ float tile[32][33];
  int k0 = blockIdx.x * 32, n0 = blockIdx.y * 32;
  int tx = threadIdx.x, ty = threadIdx.y;
  const float* src;
  int nboff;
  if (n0 < 1536)      { src = WQ; nboff = n0; }
  else if (n0 < 3072) { src = WK; nboff = n0 - 1536; }
  else                { src = WV; nboff = n0 - 3072; }
#pragma unroll
  for (int j = 0; j < 4; ++j) {
    int kk = ty + j * 8;
    tile[kk][tx] = src[(size_t)(k0 + kk) * 1536 + nboff + tx];
  }
  __syncthreads();
#pragma unroll
  for (int j = 0; j < 4; ++j) {
    int nn = ty + j * 8;
    int n = n0 + nn;
    int k = k0 + tx;
    float v = tile[tx][nn];
    if (n >= 1536) {
      int np = (n < 3072) ? (n - 1536) : (n - 3072);
      const float* cA = (n < 3072) ? cK0 : cV0;
      const float* cB = (n < 3072) ? cK1 : cV1;
      if (np < 256) {
        if (k >= 256) v += cA[(size_t)np * 1792 + (k - 256)];
      } else if (np < 768) {
        if (k >= 1024) v += cB[(size_t)(np - 256) * 1024 + (k - 1024)];
      }
    }
    Wt[(size_t)n * 2048 + k] = f2bf(v);
  }
}

// ---------------- 3b. W_O transpose+convert: Wt[n][k], n<2048, k<1536 -------
__global__ void k_pack_o(const float* __restrict__ WO, unsigned short* __restrict__ Wt) {
  __shared__ float tile[32][33];
  int k0 = blockIdx.x * 32, n0 = blockIdx.y * 32;
  int tx = threadIdx.x, ty = threadIdx.y;
#pragma unroll
  for (int j = 0; j < 4; ++j)
    tile[ty + j * 8][tx] = WO[(size_t)(k0 + ty + j * 8) * 2048 + n0 + tx];
  __syncthreads();
#pragma unroll
  for (int j = 0; j < 4; ++j) {
    int n = n0 + ty + j * 8, k = k0 + tx;
    Wt[(size_t)n * 1536 + k] = f2bf(tile[tx][ty + j * 8]);
  }
}

// ---------------- 4/6. GEMM BK=64: C = A[M][K] * Bt[N][K]^T -----------------
// 128x128 tile, 4 waves 2x2, BK=64, global_load_lds dwordx4, LDS [128][64]
// with 8-group XOR swizzle: LDS[r][g] holds global group g^(r&7).
template <bool OUT_BF16>
__global__ __launch_bounds__(256) void k_gemm_bt(const unsigned short* __restrict__ A,
                                                 const unsigned short* __restrict__ Bt,
                                                 void* __restrict__ C, int M, int N, int K) {
  __shared__ unsigned short As[128 * 64];
  __shared__ unsigned short Bs[128 * 64];
  const int tid = threadIdx.x;
  const int wave = tid >> 6, lane = tid & 63;
  const int qd = lane >> 4, ln = lane & 15;
  const int bm = blockIdx.y * 128, bn = blockIdx.x * 128;
  const int wr = wave >> 1, wc = wave & 1;
  floatx4 acc[4][4];
#pragma unroll
  for (int i = 0; i < 4; ++i)
#pragma unroll
    for (int j = 0; j < 4; ++j) acc[i][j] = (floatx4){0.f, 0.f, 0.f, 0.f};
  // staging: wave w owns rows [w*32, w*32+32); one instr = 8 rows x 64 cols.
  const int rl = lane >> 3;                        // row mod 8
  const int sg = (lane & 7) ^ rl;                  // swizzled source group
  const unsigned short* gA = A + (size_t)(bm + wave * 32 + rl) * K + sg * 8;
  const unsigned short* gB = Bt + (size_t)(bn + wave * 32 + rl) * K + sg * 8;
  unsigned short* lA = As + wave * 2048;
  unsigned short* lB = Bs + wave * 2048;
  const int l7 = ln & 7;
  for (int k0 = 0; k0 < K; k0 += 64) {
    __syncthreads();
#pragma unroll
    for (int i = 0; i < 4; ++i) {
      gload_lds16(gA + (size_t)8 * i * K + k0, lA + i * 512);
      gload_lds16(gB + (size_t)8 * i * K + k0, lB + i * 512);
    }
    __syncthreads();
#pragma unroll
    for (int h = 0; h < 2; ++h) {
      bf16x8 af[4], bfr[4];
#pragma unroll
      for (int mi = 0; mi < 4; ++mi)
        af[mi] = *(const bf16x8*)(As + (wr * 64 + mi * 16 + ln) * 64 + ((h * 4 + qd) ^ l7) * 8);
#pragma unroll
      for (int ni = 0; ni < 4; ++ni)
        bfr[ni] = *(const bf16x8*)(Bs + (wc * 64 + ni * 16 + ln) * 64 + ((h * 4 + qd) ^ l7) * 8);
#pragma unroll
      for (int mi = 0; mi < 4; ++mi)
#pragma unroll
        for (int ni = 0; ni < 4; ++ni)
          acc[mi][ni] = __builtin_amdgcn_mfma_f32_16x16x32_bf16(af[mi], bfr[ni], acc[mi][ni], 0, 0, 0);
    }
  }
#pragma unroll
  for (int mi = 0; mi < 4; ++mi)
#pragma unroll
    for (int r = 0; r < 4; ++r) {
      int row = bm + wr * 64 + mi * 16 + qd * 4 + r;
#pragma unroll
      for (int ni = 0; ni < 4; ++ni) {
        int col = bn + wc * 64 + ni * 16 + ln;
        if (OUT_BF16)
          ((unsigned short*)C)[(size_t)row * N + col] = f2bf(acc[mi][ni][r]);
        else
          ((float*)C)[(size_t)row * N + col] = acc[mi][ni][r];
      }
    }
}

// ---------------- 4b. V transpose: VT[b][d(1536)][T] from QKV cols 3072+ ----
__global__ void k_transpose_v(const unsigned short* __restrict__ QKV,
                              unsigned short* __restrict__ VT) {
  __shared__ unsigned short t[64 * 65];
  const int tt = blockIdx.x * 64, dt = blockIdx.y * 64, b = blockIdx.z;
  const int tid = threadIdx.x;
  const int r = tid >> 3, c0 = (tid & 7) * 8;
#pragma unroll
  for (int i = 0; i < 2; ++i) {
    int tok = r + i * 32;
    union { uint4 v; unsigned short u[8]; } vv;
    vv.v = *(const uint4*)(QKV + (size_t)(b * 1024 + tt + tok) * 4608 + 3072 + dt + c0);
#pragma unroll
    for (int j = 0; j < 8; ++j) t[tok * 65 + c0 + j] = vv.u[j];
  }
  __syncthreads();
#pragma unroll
  for (int i = 0; i < 2; ++i) {
    int d = r + i * 32;
    union { uint4 v; unsigned short u[8]; } vv;
#pragma unroll
    for (int j = 0; j < 8; ++j) vv.u[j] = t[(c0 + j) * 65 + d];
    *(uint4*)(VT + ((size_t)b * 1536 + dt + d) * 1024 + tt + c0) = vv.v;
  }
}

// ---------------- 5. causal flash attention, no-max softmax ----------------
// S^T = K*Q^T: C fragment = (row=key=qd*4+r, col=qrow=ln). p unnormalized
// exp2; l deferred per-lane scalar. 64-key tiles, reversed qb dispatch.
#define LDK 72   // shorts; 144B row stride
#define LDP 72
__global__ __launch_bounds__(256) void k_attn(const unsigned short* __restrict__ QKV,
                                              const unsigned short* __restrict__ VT,
                                              unsigned short* __restrict__ Oout) {
  __shared__ unsigned short Ks[64 * LDK];
  __shared__ unsigned short VTs[64 * LDK];   // VTs[d][key]
  __shared__ unsigned short Pl[4][16 * LDP]; // wave-private P staging
  const int tid = threadIdx.x;
  const int wave = tid >> 6, lane = tid & 63;
  const int qd = lane >> 4, ln = lane & 15;
  const int qb = (int)gridDim.x - 1 - (int)blockIdx.x;   // big blocks first
  const int gh = blockIdx.y, b = blockIdx.z;
  const int T = 1024, LD = 4608;
  const size_t rowbase = (size_t)b * T * LD;
  const int qcol = 64 * gh, kcol = 1536 + 64 * gh;
  const int q0w = qb * 64 + wave * 16;
  const unsigned short* VTg = VT + ((size_t)b * 1536 + 64 * gh) * 1024;
  const float SCALE = 0.18033688f;  // 1/sqrt(64) * log2(e)
  const int qrow = q0w + ln;        // this lane's q-row (S^T layout)

  bf16x8 aq0, aq1;  // Q as B-operand: Q[qrow][d]
  {
    const unsigned short* qp = QKV + rowbase + (size_t)(q0w + ln) * LD + qcol;
    aq0 = *(const bf16x8*)(qp + qd * 8);
    aq1 = *(const bf16x8*)(qp + 32 + qd * 8);
  }
  floatx4 Oacc[4];
#pragma unroll
  for (int i = 0; i < 4; ++i) Oacc[i] = (floatx4){0.f, 0.f, 0.f, 0.f};
  float l_lane = 0.f;

  const int rr = tid >> 3, c0 = (tid & 7) * 8;
  for (int jt = 0; jt <= qb; ++jt) {
    const int jk = jt * 64;
    const bool diag = (jt == qb);
    __syncthreads();
#pragma unroll
    for (int i = 0; i < 2; ++i) {
      int kr = rr + i * 32;
      uint4 vk = *(const uint4*)(QKV + rowbase + (size_t)(jk + kr) * LD + kcol + c0);
      *(uint4*)(Ks + kr * LDK + c0) = vk;
      uint4 vv = *(const uint4*)(VTg + (size_t)kr * 1024 + jk + c0);
      *(uint4*)(VTs + kr * LDK + c0) = vv;
    }
    __syncthreads();

    // S^T = K Q^T : A = K[key][d] (frag h covers keys h*16..+16), B = Q
    floatx4 Sc[4];
#pragma unroll
    for (int h = 0; h < 4; ++h) {
      Sc[h] = (floatx4){0.f, 0.f, 0.f, 0.f};
      bf16x8 a0 = *(const bf16x8*)(Ks + (h * 16 + ln) * LDK + qd * 8);
      bf16x8 a1 = *(const bf16x8*)(Ks + (h * 16 + ln) * LDK + 32 + qd * 8);
      Sc[h] = __builtin_amdgcn_mfma_f32_16x16x32_bf16(a0, aq0, Sc[h], 0, 0, 0);
      Sc[h] = __builtin_amdgcn_mfma_f32_16x16x32_bf16(a1, aq1, Sc[h], 0, 0, 0);
    }
    // p = exp2(min(s*SCALE, 80)), masked on diag tile; accumulate l per-lane
    unsigned short* pw = Pl[wave];
#pragma unroll
    for (int h = 0; h < 4; ++h) {
      union { unsigned short u[4]; uint2 v; } pk;
#pragma unroll
      for (int r = 0; r < 4; ++r) {
        float v = fminf(Sc[h][r] * SCALE, 80.f);
        float p = __builtin_amdgcn_exp2f(v);
        if (diag) {
          int key = jk + h * 16 + qd * 4 + r;
          if (key > qrow) p = 0.f;
        }
        l_lane += p;
        pk.u[r] = f2bf(p);
      }
      *(uint2*)(pw + ln * LDP + h * 16 + qd * 4) = pk.v;   // 8B-aligned
    }
    __asm__ volatile("s_waitcnt lgkmcnt(0)" ::: "memory");
    // P as A-operand: A[m=qrow=ln][k=key=qd*8+j]
    bf16x8 pa0 = *(const bf16x8*)(pw + ln * LDP + qd * 8);
    bf16x8 pa1 = *(const bf16x8*)(pw + ln * LDP + 32 + qd * 8);
#pragma unroll
    for (int nc = 0; nc < 4; ++nc) {
      bf16x8 bv0 = *(const bf16x8*)(VTs + (nc * 16 + ln) * LDK + qd * 8);
      bf16x8 bv1 = *(const bf16x8*)(VTs + (nc * 16 + ln) * LDK + 32 + qd * 8);
      Oacc[nc] = __builtin_amdgcn_mfma_f32_16x16x32_bf16(pa0, bv0, Oacc[nc], 0, 0, 0);
      Oacc[nc] = __builtin_amdgcn_mfma_f32_16x16x32_bf16(pa1, bv1, Oacc[nc], 0, 0, 0);
    }
  }
  // l: reduce across the 4 qd-groups sharing each ln (full sum lands in all)
  l_lane += __shfl_xor(l_lane, 16, 64);
  l_lane += __shfl_xor(l_lane, 32, 64);
  // Oacc row = qd*4+r needs l of q-row qd*4+r, held by lane (qd*4+r)
#pragma unroll
  for (int r = 0; r < 4; ++r) {
    float inv = 1.0f / __shfl(l_lane, qd * 4 + r, 64);
    size_t row = (size_t)b * T + q0w + qd * 4 + r;
#pragma unroll
    for (int nc = 0; nc < 4; ++nc)
      Oout[row * 1536 + 64 * gh + nc * 16 + ln] = f2bf(Oacc[nc][r] * inv);
  }
}

// ---------------------------------------------------------------------------
extern "C" void kernel_launch(void* const* d_in, const int* in_sizes, int n_in,
                              void* d_out, int out_size, void* d_ws, size_t ws_size,
                              hipStream_t stream) {
  (void)in_sizes; (void)n_in; (void)out_size; (void)ws_size;
  const float* x   = (const float*)d_in[0];
  const float* WQ  = (const float*)d_in[1];
  const float* WK  = (const float*)d_in[2];
  const float* WV  = (const float*)d_in[3];
  const float* WO  = (const float*)d_in[4];
  const float* FK0 = (const float*)d_in[5];
  const float* PK0 = (const float*)d_in[6];
  const float* FV0 = (const float*)d_in[7];
  const float* PV0 = (const float*)d_in[8];
  const float* FK1 = (const float*)d_in[9];
  const float* PK1 = (const float*)d_in[10];
  const float* FV1 = (const float*)d_in[11];
  const float* PV1 = (const float*)d_in[12];

  char* ws = (char*)d_ws;
  unsigned short* X16   = (unsigned short*)(ws + 0);          // 16 MB (dead after GEMM1)
  unsigned short* VTb   = X16;                                 // VT aliases X16
  unsigned short* WTQKV = (unsigned short*)(ws + 16777216);   // 18 MB
  unsigned short* QKV   = (unsigned short*)(ws + 35651584);   // 36 MB
  unsigned short* ATT   = (unsigned short*)(ws + 73400320);   // 12 MB
  unsigned short* WTO   = (unsigned short*)(ws + 85983232);   //  6 MB
  float* WCK0 = (float*)(ws + 92274688);
  float* WCV0 = (float*)(ws + 94109696);
  float* WCK1 = (float*)(ws + 95944704);
  float* WCV1 = (float*)(ws + 98041856);

  k_cvt_x<<<8192, 256, 0, stream>>>(x, X16, 2097152);
  k_build_all<<<7680, 256, 0, stream>>>(FK0, PK0, WCK0, FV0, PV0, WCV0,
                                        FK1, PK1, WCK1, FV1, PV1, WCV1);
  k_pack_qkv<<<dim3(64, 144), dim3(32, 8), 0, stream>>>(WQ, WK, WV, WCK0, WCV0, WCK1, WCV1, WTQKV);
  k_pack_o<<<dim3(48, 64), dim3(32, 8), 0, stream>>>(WO, WTO);
  k_gemm_bt<true><<<dim3(36, 32), 256, 0, stream>>>(X16, WTQKV, QKV, 4096, 4608, 2048);
  k_transpose_v<<<dim3(16, 24, 4), 256, 0, stream>>>(QKV, VTb);
  k_attn<<<dim3(16, 24, 4), 256, 0, stream>>>(QKV, VTb, ATT);
  k_gemm_bt<false><<<dim3(16, 32), 256, 0, stream>>>(ATT, WTO, d_out, 4096, 2048, 1536);
}

// Round 5
// 334.333 us; speedup vs baseline: 1.2533x; 1.0936x over previous
//
#include <hip/hip_runtime.h>

// ---------------------------------------------------------------------------
// MatryoshkaAttention on MI355X (gfx950), bf16 MFMA pipeline. Round 5.
//
// Changes vs R4:
//  - Block-UT sparsity exploited exactly: per-column-block K_eff in both
//    GEMMs (Q cols: 256/1024/2048; W_O cols: 256/768/1536).
//  - k_attn: 128-row Q tiles (2 frags/wave), K/V staged via global_load_lds
//    width=16 with the 8-group XOR swizzle (no VGPR round-trip, no conflicts).
//  - Prep fused to ONE kernel (cvt_x + pack_qkv-with-inline-corrections +
//    pack_o); correction GEMM done per-tile from LDS-staged F/P (8 FMA/elem).
//    5 launches total.
// ---------------------------------------------------------------------------

typedef short bf16x8 __attribute__((ext_vector_type(8)));
typedef float floatx4 __attribute__((ext_vector_type(4)));

__device__ __forceinline__ unsigned short f2bf(float f) {
  unsigned u = __builtin_bit_cast(unsigned, f);
  u += 0x7fffu + ((u >> 16) & 1u);           // RNE
  return (unsigned short)(u >> 16);
}

__device__ __forceinline__ void gload_lds16(const unsigned short* g, unsigned short* l) {
  __builtin_amdgcn_global_load_lds((const __attribute__((address_space(1))) unsigned int*)g,
                                   (__attribute__((address_space(3))) unsigned int*)l, 16, 0, 0);
}

// ---------------- 1. fused prep: cvt_x | pack_qkv(+corr) | pack_o ----------
// blocks [0,8192): x->bf16 ; [8192,17408): W_QKV pack ; [17408,20480): W_O.
__global__ __launch_bounds__(256) void k_prep(
    const float* __restrict__ x, unsigned short* __restrict__ X16,
    const float* __restrict__ WQ, const float* __restrict__ WK, const float* __restrict__ WV,
    const float* __restrict__ FK0, const float* __restrict__ PK0,
    const float* __restrict__ FV0, const float* __restrict__ PV0,
    const float* __restrict__ FK1, const float* __restrict__ PK1,
    const float* __restrict__ FV1, const float* __restrict__ PV1,
    unsigned short* __restrict__ WTQKV,
    const float* __restrict__ WO, unsigned short* __restrict__ WTO) {
  __shared__ float tile[32][33];
  __shared__ float Fs[32][9];
  __shared__ float Ps[8][32];
  const int bid = blockIdx.x;
  const int tid = threadIdx.x;
  if (bid < 8192) {                       // ---- x -> bf16 (float4 per thread)
    int i = bid * 256 + tid;
    float4 v = ((const float4*)x)[i];
    union { unsigned short u[4]; uint2 v2; } o;
    o.u[0] = f2bf(v.x); o.u[1] = f2bf(v.y); o.u[2] = f2bf(v.z); o.u[3] = f2bf(v.w);
    ((uint2*)X16)[i] = o.v2;
    return;
  }
  const int tx = tid & 31, ty = tid >> 5;
  if (bid < 17408) {                      // ---- W_QKV transpose + corrections
    int t = bid - 8192;
    int k0 = (t & 63) * 32, n0 = (t >> 6) * 32;
    const float* src; int nboff;
    if (n0 < 1536)      { src = WQ; nboff = n0; }
    else if (n0 < 3072) { src = WK; nboff = n0 - 1536; }
    else                { src = WV; nboff = n0 - 3072; }
#pragma unroll
    for (int j = 0; j < 4; ++j) {
      int kk = ty + j * 8;
      tile[kk][tx] = src[(size_t)(k0 + kk) * 1536 + nboff + tx];
    }
    // tile-uniform correction selection
    int corrsel = 0; const float* Fsrc = nullptr; const float* Psrc = nullptr;
    int h = 0, d0 = 0, fs = 0, koff = 0;
    if (n0 >= 1536) {
      bool isK = (n0 < 3072);
      int np0 = isK ? (n0 - 1536) : (n0 - 3072);
      if (np0 < 256) {
        if (k0 >= 256) { corrsel = 1; Fsrc = isK ? FK0 : FV0; Psrc = isK ? PK0 : PV0;
                         h = np0 >> 6; d0 = np0 & 63; fs = 32; koff = k0 - 256; }
      } else if (np0 < 768) {
        if (k0 >= 1024) { corrsel = 1; Fsrc = isK ? FK1 : FV1; Psrc = isK ? PK1 : PV1;
                          h = (np0 - 256) >> 6; d0 = (np0 - 256) & 63; fs = 64; koff = k0 - 1024; }
      }
    }
    if (corrsel) {
      Fs[tid >> 3][tid & 7] = Fsrc[(size_t)(koff + (tid >> 3)) * fs + h * 8 + (tid & 7)];
      Ps[tid >> 5][tid & 31] = Psrc[h * 512 + (tid >> 5) * 64 + d0 + (tid & 31)];
    }
    __syncthreads();
#pragma unroll
    for (int j = 0; j < 4; ++j) {
      int nn = ty + j * 8;
      float v = tile[tx][nn];
      if (corrsel) {
        float c = 0.f;
#pragma unroll
        for (int r = 0; r < 8; ++r) c += Fs[tx][r] * Ps[r][nn];
        v += c;
      }
      WTQKV[(size_t)(n0 + nn) * 2048 + k0 + tx] = f2bf(v);
    }
  } else {                                // ---- W_O transpose
    int t = bid - 17408;
    int k0 = (t % 48) * 32, n0 = (t / 48) * 32;
#pragma unroll
    for (int j = 0; j < 4; ++j)
      tile[ty + j * 8][tx] = WO[(size_t)(k0 + ty + j * 8) * 2048 + n0 + tx];
    __syncthreads();
#pragma unroll
    for (int j = 0; j < 4; ++j)
      WTO[(size_t)(n0 + ty + j * 8) * 1536 + k0 + tx] = f2bf(tile[tx][ty + j * 8]);
  }
}

// ---------------- 4/6. GEMM BK=64, variable K_eff per column block ----------
// 128x128 tile, 4 waves 2x2, global_load_lds dwordx4, LDS [128][64] with
// 8-group XOR swizzle. MODE 0: QKV projection; MODE 1: output projection.
template <bool OUT_BF16, int MODE>
__global__ __launch_bounds__(256) void k_gemm_bt(const unsigned short* __restrict__ A,
                                                 const unsigned short* __restrict__ Bt,
                                                 void* __restrict__ C, int M, int N, int K) {
  __shared__ unsigned short As[128 * 64];
  __shared__ unsigned short Bs[128 * 64];
  const int tid = threadIdx.x;
  const int wave = tid >> 6, lane = tid & 63;
  const int qd = lane >> 4, ln = lane & 15;
  const int bm = blockIdx.y * 128, bn = blockIdx.x * 128;
  const int wr = wave >> 1, wc = wave & 1;
  // exact block-UT sparsity: columns of this block only need K_eff inputs
  int Keff;
  if (MODE == 0) Keff = (bn < 256) ? 256 : (bn < 768 ? 1024 : 2048);
  else           Keff = (bn < 256) ? 256 : (bn < 1024 ? 768 : 1536);
  floatx4 acc[4][4];
#pragma unroll
  for (int i = 0; i < 4; ++i)
#pragma unroll
    for (int j = 0; j < 4; ++j) acc[i][j] = (floatx4){0.f, 0.f, 0.f, 0.f};
  const int rl = lane >> 3;                        // row mod 8
  const int sg = (lane & 7) ^ rl;                  // swizzled source group
  const unsigned short* gA = A + (size_t)(bm + wave * 32 + rl) * K + sg * 8;
  const unsigned short* gB = Bt + (size_t)(bn + wave * 32 + rl) * K + sg * 8;
  unsigned short* lA = As + wave * 2048;
  unsigned short* lB = Bs + wave * 2048;
  const int l7 = ln & 7;
  for (int k0 = 0; k0 < Keff; k0 += 64) {
    __syncthreads();
#pragma unroll
    for (int i = 0; i < 4; ++i) {
      gload_lds16(gA + (size_t)8 * i * K + k0, lA + i * 512);
      gload_lds16(gB + (size_t)8 * i * K + k0, lB + i * 512);
    }
    __syncthreads();
#pragma unroll
    for (int h = 0; h < 2; ++h) {
      bf16x8 af[4], bfr[4];
#pragma unroll
      for (int mi = 0; mi < 4; ++mi)
        af[mi] = *(const bf16x8*)(As + (wr * 64 + mi * 16 + ln) * 64 + ((h * 4 + qd) ^ l7) * 8);
#pragma unroll
      for (int ni = 0; ni < 4; ++ni)
        bfr[ni] = *(const bf16x8*)(Bs + (wc * 64 + ni * 16 + ln) * 64 + ((h * 4 + qd) ^ l7) * 8);
#pragma unroll
      for (int mi = 0; mi < 4; ++mi)
#pragma unroll
        for (int ni = 0; ni < 4; ++ni)
          acc[mi][ni] = __builtin_amdgcn_mfma_f32_16x16x32_bf16(af[mi], bfr[ni], acc[mi][ni], 0, 0, 0);
    }
  }
#pragma unroll
  for (int mi = 0; mi < 4; ++mi)
#pragma unroll
    for (int r = 0; r < 4; ++r) {
      int row = bm + wr * 64 + mi * 16 + qd * 4 + r;
#pragma unroll
      for (int ni = 0; ni < 4; ++ni) {
        int col = bn + wc * 64 + ni * 16 + ln;
        if (OUT_BF16)
          ((unsigned short*)C)[(size_t)row * N + col] = f2bf(acc[mi][ni][r]);
        else
          ((float*)C)[(size_t)row * N + col] = acc[mi][ni][r];
      }
    }
}

// ---------------- 4b. V transpose: VT[b][d(1536)][T] from QKV cols 3072+ ----
__global__ void k_transpose_v(const unsigned short* __restrict__ QKV,
                              unsigned short* __restrict__ VT) {
  __shared__ unsigned short t[64 * 65];
  const int tt = blockIdx.x * 64, dt = blockIdx.y * 64, b = blockIdx.z;
  const int tid = threadIdx.x;
  const int r = tid >> 3, c0 = (tid & 7) * 8;
#pragma unroll
  for (int i = 0; i < 2; ++i) {
    int tok = r + i * 32;
    union { uint4 v; unsigned short u[8]; } vv;
    vv.v = *(const uint4*)(QKV + (size_t)(b * 1024 + tt + tok) * 4608 + 3072 + dt + c0);
#pragma unroll
    for (int j = 0; j < 8; ++j) t[tok * 65 + c0 + j] = vv.u[j];
  }
  __syncthreads();
#pragma unroll
  for (int i = 0; i < 2; ++i) {
    int d = r + i * 32;
    union { uint4 v; unsigned short u[8]; } vv;
#pragma unroll
    for (int j = 0; j < 8; ++j) vv.u[j] = t[(c0 + j) * 65 + d];
    *(uint4*)(VT + ((size_t)b * 1536 + dt + d) * 1024 + tt + c0) = vv.v;
  }
}

// ---------------- 5. causal flash attention, 128-row Q tiles ----------------
// grid (8 qtiles [reversed], 24 heads, 4 batch), block 256 = 4 waves.
// Each wave: 2 q-frags (16 rows each, 64 apart). No-max exp2 softmax with
// deferred per-lane l. K/V staged by global_load_lds w/ XOR swizzle.
#define LDP 72
__global__ __launch_bounds__(256) void k_attn(const unsigned short* __restrict__ QKV,
                                              const unsigned short* __restrict__ VT,
                                              unsigned short* __restrict__ Oout) {
  __shared__ unsigned short Ks[64 * 64];
  __shared__ unsigned short VTs[64 * 64];    // VTs[d][key], swizzled groups
  __shared__ unsigned short Pl[4][2][16 * LDP];
  const int tid = threadIdx.x;
  const int wave = tid >> 6, lane = tid & 63;
  const int qd = lane >> 4, ln = lane & 15;
  const int qb = (int)gridDim.x - 1 - (int)blockIdx.x;   // big blocks first
  const int gh = blockIdx.y, b = blockIdx.z;
  const int T = 1024, LD = 4608;
  const size_t rowbase = (size_t)b * T * LD;
  const int qcol = 64 * gh, kcol = 1536 + 64 * gh;
  const unsigned short* VTg = VT + ((size_t)b * 1536 + 64 * gh) * 1024;
  const float SCALE = 0.18033688f;  // 1/sqrt(64) * log2(e)
  const int q0 = qb * 128 + wave * 16;       // frag j adds j*64

  bf16x8 aq[2][2];
#pragma unroll
  for (int j = 0; j < 2; ++j) {
    const unsigned short* qp = QKV + rowbase + (size_t)(q0 + j * 64 + ln) * LD + qcol;
    aq[j][0] = *(const bf16x8*)(qp + qd * 8);
    aq[j][1] = *(const bf16x8*)(qp + 32 + qd * 8);
  }
  floatx4 Oacc[2][4];
#pragma unroll
  for (int j = 0; j < 2; ++j)
#pragma unroll
    for (int i = 0; i < 4; ++i) Oacc[j][i] = (floatx4){0.f, 0.f, 0.f, 0.f};
  float l_lane[2] = {0.f, 0.f};

  // DMA staging: wave w stages rows [w*16, w*16+16) of both K and VT.
  const int drow = lane >> 3;                 // 0..7
  const int dgrp = (lane & 7) ^ drow;         // swizzled source group
  const unsigned short* gK = QKV + rowbase + (size_t)(wave * 16 + drow) * LD + kcol + dgrp * 8;
  const unsigned short* gV = VTg + (size_t)(wave * 16 + drow) * 1024 + dgrp * 8;
  unsigned short* lK = Ks + wave * 16 * 64;
  unsigned short* lV = VTs + wave * 16 * 64;
  const int l7 = ln & 7;

  const int ntiles = 2 * qb + 2;
  for (int jt = 0; jt < ntiles; ++jt) {
    const int jk = jt * 64;
    __syncthreads();
    gload_lds16(gK + (size_t)jk * LD, lK);
    gload_lds16(gK + (size_t)(jk + 8) * LD, lK + 512);
    gload_lds16(gV + jk, lV);
    gload_lds16(gV + 8 * 1024 + jk, lV + 512);
    __syncthreads();

#pragma unroll
    for (int j = 0; j < 2; ++j) {
      if (j == 0 && jt == ntiles - 1) continue;   // frag0 fully masked there
      // S^T = K Q^T : A = K[key][d] (frag h = keys h*16..+16), B = Q
      floatx4 Sc[4];
#pragma unroll
      for (int h = 0; h < 4; ++h) {
        Sc[h] = (floatx4){0.f, 0.f, 0.f, 0.f};
        bf16x8 a0 = *(const bf16x8*)(Ks + (h * 16 + ln) * 64 + (qd ^ l7) * 8);
        bf16x8 a1 = *(const bf16x8*)(Ks + (h * 16 + ln) * 64 + ((4 + qd) ^ l7) * 8);
        Sc[h] = __builtin_amdgcn_mfma_f32_16x16x32_bf16(a0, aq[j][0], Sc[h], 0, 0, 0);
        Sc[h] = __builtin_amdgcn_mfma_f32_16x16x32_bf16(a1, aq[j][1], Sc[h], 0, 0, 0);
      }
      const bool diag = (jt == 2 * qb + j);
      const int qrow = q0 + j * 64 + ln;
      unsigned short* pw = Pl[wave][j];
#pragma unroll
      for (int h = 0; h < 4; ++h) {
        union { unsigned short u[4]; uint2 v; } pk;
#pragma unroll
        for (int r = 0; r < 4; ++r) {
          float v = fminf(Sc[h][r] * SCALE, 80.f);
          float p = __builtin_amdgcn_exp2f(v);
          if (diag) {
            int key = jk + h * 16 + qd * 4 + r;
            if (key > qrow) p = 0.f;
          }
          l_lane[j] += p;
          pk.u[r] = f2bf(p);
        }
        *(uint2*)(pw + ln * LDP + h * 16 + qd * 4) = pk.v;
      }
      __asm__ volatile("s_waitcnt lgkmcnt(0)" ::: "memory");
      bf16x8 pa0 = *(const bf16x8*)(pw + ln * LDP + qd * 8);
      bf16x8 pa1 = *(const bf16x8*)(pw + ln * LDP + 32 + qd * 8);
#pragma unroll
      for (int nc = 0; nc < 4; ++nc) {
        bf16x8 bv0 = *(const bf16x8*)(VTs + (nc * 16 + ln) * 64 + (qd ^ l7) * 8);
        bf16x8 bv1 = *(const bf16x8*)(VTs + (nc * 16 + ln) * 64 + ((4 + qd) ^ l7) * 8);
        Oacc[j][nc] = __builtin_amdgcn_mfma_f32_16x16x32_bf16(pa0, bv0, Oacc[j][nc], 0, 0, 0);
        Oacc[j][nc] = __builtin_amdgcn_mfma_f32_16x16x32_bf16(pa1, bv1, Oacc[j][nc], 0, 0, 0);
      }
    }
  }
  // l: sum the 4 qd-groups per ln, then normalize + store
#pragma unroll
  for (int j = 0; j < 2; ++j) {
    float l = l_lane[j];
    l += __shfl_xor(l, 16, 64);
    l += __shfl_xor(l, 32, 64);
#pragma unroll
    for (int r = 0; r < 4; ++r) {
      float inv = 1.0f / __shfl(l, qd * 4 + r, 64);
      size_t row = (size_t)b * T + q0 + j * 64 + qd * 4 + r;
#pragma unroll
      for (int nc = 0; nc < 4; ++nc)
        Oout[row * 1536 + 64 * gh + nc * 16 + ln] = f2bf(Oacc[j][nc][r] * inv);
    }
  }
}

// ---------------------------------------------------------------------------
extern "C" void kernel_launch(void* const* d_in, const int* in_sizes, int n_in,
                              void* d_out, int out_size, void* d_ws, size_t ws_size,
                              hipStream_t stream) {
  (void)in_sizes; (void)n_in; (void)out_size; (void)ws_size;
  const float* x   = (const float*)d_in[0];
  const float* WQ  = (const float*)d_in[1];
  const float* WK  = (const float*)d_in[2];
  const float* WV  = (const float*)d_in[3];
  const float* WO  = (const float*)d_in[4];
  const float* FK0 = (const float*)d_in[5];
  const float* PK0 = (const float*)d_in[6];
  const float* FV0 = (const float*)d_in[7];
  const float* PV0 = (const float*)d_in[8];
  const float* FK1 = (const float*)d_in[9];
  const float* PK1 = (const float*)d_in[10];
  const float* FV1 = (const float*)d_in[11];
  const float* PV1 = (const float*)d_in[12];

  char* ws = (char*)d_ws;
  unsigned short* X16   = (unsigned short*)(ws + 0);          // 16 MB (dead after GEMM1)
  unsigned short* VTb   = X16;                                 // VT aliases X16
  unsigned short* WTQKV = (unsigned short*)(ws + 16777216);   // 18 MB
  unsigned short* QKV   = (unsigned short*)(ws + 35651584);   // 36 MB
  unsigned short* ATT   = (unsigned short*)(ws + 73400320);   // 12 MB
  unsigned short* WTO   = (unsigned short*)(ws + 85983232);   //  6 MB

  k_prep<<<20480, 256, 0, stream>>>(x, X16, WQ, WK, WV,
                                    FK0, PK0, FV0, PV0, FK1, PK1, FV1, PV1,
                                    WTQKV, WO, WTO);
  k_gemm_bt<true, 0><<<dim3(36, 32), 256, 0, stream>>>(X16, WTQKV, QKV, 4096, 4608, 2048);
  k_transpose_v<<<dim3(16, 24, 4), 256, 0, stream>>>(QKV, VTb);
  k_attn<<<dim3(8, 24, 4), 256, 0, stream>>>(QKV, VTb, ATT);
  k_gemm_bt<false, 1><<<dim3(16, 32), 256, 0, stream>>>(ATT, WTO, d_out, 4096, 2048, 1536);
}

// Round 6
// 332.139 us; speedup vs baseline: 1.2616x; 1.0066x over previous
//
#include <hip/hip_runtime.h>

// ---------------------------------------------------------------------------
// MatryoshkaAttention on MI355X (gfx950), bf16 MFMA pipeline. Round 6.
//
// Changes vs R5:
//  - k_gemm_bt: 1D grid with LPT (longest-first) block ordering — Keff-max
//    column blocks dispatch first (row-major within class for L2 locality),
//    short columns fill the tail. Fixes R5's load-imbalance regression.
//  - k_attn: 128-key x 128-query tiles (halves barriers/staging rounds);
//    diagonal tile computes only the live triangle halves per frag.
// ---------------------------------------------------------------------------

typedef short bf16x8 __attribute__((ext_vector_type(8)));
typedef float floatx4 __attribute__((ext_vector_type(4)));

__device__ __forceinline__ unsigned short f2bf(float f) {
  unsigned u = __builtin_bit_cast(unsigned, f);
  u += 0x7fffu + ((u >> 16) & 1u);           // RNE
  return (unsigned short)(u >> 16);
}

__device__ __forceinline__ void gload_lds16(const unsigned short* g, unsigned short* l) {
  __builtin_amdgcn_global_load_lds((const __attribute__((address_space(1))) unsigned int*)g,
                                   (__attribute__((address_space(3))) unsigned int*)l, 16, 0, 0);
}

// ---------------- 1. fused prep: cvt_x | pack_qkv(+corr) | pack_o ----------
// blocks [0,8192): x->bf16 ; [8192,17408): W_QKV pack ; [17408,20480): W_O.
__global__ __launch_bounds__(256) void k_prep(
    const float* __restrict__ x, unsigned short* __restrict__ X16,
    const float* __restrict__ WQ, const float* __restrict__ WK, const float* __restrict__ WV,
    const float* __restrict__ FK0, const float* __restrict__ PK0,
    const float* __restrict__ FV0, const float* __restrict__ PV0,
    const float* __restrict__ FK1, const float* __restrict__ PK1,
    const float* __restrict__ FV1, const float* __restrict__ PV1,
    unsigned short* __restrict__ WTQKV,
    const float* __restrict__ WO, unsigned short* __restrict__ WTO) {
  __shared__ float tile[32][33];
  __shared__ float Fs[32][9];
  __shared__ float Ps[8][32];
  const int bid = blockIdx.x;
  const int tid = threadIdx.x;
  if (bid < 8192) {                       // ---- x -> bf16 (float4 per thread)
    int i = bid * 256 + tid;
    float4 v = ((const float4*)x)[i];
    union { unsigned short u[4]; uint2 v2; } o;
    o.u[0] = f2bf(v.x); o.u[1] = f2bf(v.y); o.u[2] = f2bf(v.z); o.u[3] = f2bf(v.w);
    ((uint2*)X16)[i] = o.v2;
    return;
  }
  const int tx = tid & 31, ty = tid >> 5;
  if (bid < 17408) {                      // ---- W_QKV transpose + corrections
    int t = bid - 8192;
    int k0 = (t & 63) * 32, n0 = (t >> 6) * 32;
    const float* src; int nboff;
    if (n0 < 1536)      { src = WQ; nboff = n0; }
    else if (n0 < 3072) { src = WK; nboff = n0 - 1536; }
    else                { src = WV; nboff = n0 - 3072; }
#pragma unroll
    for (int j = 0; j < 4; ++j) {
      int kk = ty + j * 8;
      tile[kk][tx] = src[(size_t)(k0 + kk) * 1536 + nboff + tx];
    }
    int corrsel = 0; const float* Fsrc = nullptr; const float* Psrc = nullptr;
    int h = 0, d0 = 0, fs = 0, koff = 0;
    if (n0 >= 1536) {
      bool isK = (n0 < 3072);
      int np0 = isK ? (n0 - 1536) : (n0 - 3072);
      if (np0 < 256) {
        if (k0 >= 256) { corrsel = 1; Fsrc = isK ? FK0 : FV0; Psrc = isK ? PK0 : PV0;
                         h = np0 >> 6; d0 = np0 & 63; fs = 32; koff = k0 - 256; }
      } else if (np0 < 768) {
        if (k0 >= 1024) { corrsel = 1; Fsrc = isK ? FK1 : FV1; Psrc = isK ? PK1 : PV1;
                          h = (np0 - 256) >> 6; d0 = (np0 - 256) & 63; fs = 64; koff = k0 - 1024; }
      }
    }
    if (corrsel) {
      Fs[tid >> 3][tid & 7] = Fsrc[(size_t)(koff + (tid >> 3)) * fs + h * 8 + (tid & 7)];
      Ps[tid >> 5][tid & 31] = Psrc[h * 512 + (tid >> 5) * 64 + d0 + (tid & 31)];
    }
    __syncthreads();
#pragma unroll
    for (int j = 0; j < 4; ++j) {
      int nn = ty + j * 8;
      float v = tile[tx][nn];
      if (corrsel) {
        float c = 0.f;
#pragma unroll
        for (int r = 0; r < 8; ++r) c += Fs[tx][r] * Ps[r][nn];
        v += c;
      }
      WTQKV[(size_t)(n0 + nn) * 2048 + k0 + tx] = f2bf(v);
    }
  } else {                                // ---- W_O transpose
    int t = bid - 17408;
    int k0 = (t % 48) * 32, n0 = (t / 48) * 32;
#pragma unroll
    for (int j = 0; j < 4; ++j)
      tile[ty + j * 8][tx] = WO[(size_t)(k0 + ty + j * 8) * 2048 + n0 + tx];
    __syncthreads();
#pragma unroll
    for (int j = 0; j < 4; ++j)
      WTO[(size_t)(n0 + ty + j * 8) * 1536 + k0 + tx] = f2bf(tile[tx][ty + j * 8]);
  }
}

// ---------------- 4/6. GEMM BK=64, Keff per column block, LPT dispatch ------
// 1D grid; long (Keff-max) blocks first, row-major within class.
// MODE 0: QKV (N=4608, 36 cols: long bx6..35, mid bx2..5, short bx0..1)
// MODE 1: out (N=2048, 16 cols: long bx8..15, mid bx2..7, short bx0..1)
template <bool OUT_BF16, int MODE>
__global__ __launch_bounds__(256) void k_gemm_bt(const unsigned short* __restrict__ A,
                                                 const unsigned short* __restrict__ Bt,
                                                 void* __restrict__ C, int M, int N, int K) {
  __shared__ unsigned short As[128 * 64];
  __shared__ unsigned short Bs[128 * 64];
  const int tid = threadIdx.x;
  const int wave = tid >> 6, lane = tid & 63;
  const int qd = lane >> 4, ln = lane & 15;
  int idx = blockIdx.x, bx, by;
  if (MODE == 0) {
    if (idx < 960)       { bx = 6 + idx % 30; by = idx / 30; }
    else if (idx < 1088) { int t = idx - 960; bx = 2 + (t & 3); by = t >> 2; }
    else                 { int t = idx - 1088; bx = t & 1; by = t >> 1; }
  } else {
    if (idx < 256)       { bx = 8 + (idx & 7); by = idx >> 3; }
    else if (idx < 448)  { int t = idx - 256; bx = 2 + t % 6; by = t / 6; }
    else                 { int t = idx - 448; bx = t & 1; by = t >> 1; }
  }
  const int bm = by * 128, bn = bx * 128;
  const int wr = wave >> 1, wc = wave & 1;
  int Keff;
  if (MODE == 0) Keff = (bn < 256) ? 256 : (bn < 768 ? 1024 : 2048);
  else           Keff = (bn < 256) ? 256 : (bn < 1024 ? 768 : 1536);
  floatx4 acc[4][4];
#pragma unroll
  for (int i = 0; i < 4; ++i)
#pragma unroll
    for (int j = 0; j < 4; ++j) acc[i][j] = (floatx4){0.f, 0.f, 0.f, 0.f};
  const int rl = lane >> 3;                        // row mod 8
  const int sg = (lane & 7) ^ rl;                  // swizzled source group
  const unsigned short* gA = A + (size_t)(bm + wave * 32 + rl) * K + sg * 8;
  const unsigned short* gB = Bt + (size_t)(bn + wave * 32 + rl) * K + sg * 8;
  unsigned short* lA = As + wave * 2048;
  unsigned short* lB = Bs + wave * 2048;
  const int l7 = ln & 7;
  for (int k0 = 0; k0 < Keff; k0 += 64) {
    __syncthreads();
#pragma unroll
    for (int i = 0; i < 4; ++i) {
      gload_lds16(gA + (size_t)8 * i * K + k0, lA + i * 512);
      gload_lds16(gB + (size_t)8 * i * K + k0, lB + i * 512);
    }
    __syncthreads();
#pragma unroll
    for (int h = 0; h < 2; ++h) {
      bf16x8 af[4], bfr[4];
#pragma unroll
      for (int mi = 0; mi < 4; ++mi)
        af[mi] = *(const bf16x8*)(As + (wr * 64 + mi * 16 + ln) * 64 + ((h * 4 + qd) ^ l7) * 8);
#pragma unroll
      for (int ni = 0; ni < 4; ++ni)
        bfr[ni] = *(const bf16x8*)(Bs + (wc * 64 + ni * 16 + ln) * 64 + ((h * 4 + qd) ^ l7) * 8);
#pragma unroll
      for (int mi = 0; mi < 4; ++mi)
#pragma unroll
        for (int ni = 0; ni < 4; ++ni)
          acc[mi][ni] = __builtin_amdgcn_mfma_f32_16x16x32_bf16(af[mi], bfr[ni], acc[mi][ni], 0, 0, 0);
    }
  }
#pragma unroll
  for (int mi = 0; mi < 4; ++mi)
#pragma unroll
    for (int r = 0; r < 4; ++r) {
      int row = bm + wr * 64 + mi * 16 + qd * 4 + r;
#pragma unroll
      for (int ni = 0; ni < 4; ++ni) {
        int col = bn + wc * 64 + ni * 16 + ln;
        if (OUT_BF16)
          ((unsigned short*)C)[(size_t)row * N + col] = f2bf(acc[mi][ni][r]);
        else
          ((float*)C)[(size_t)row * N + col] = acc[mi][ni][r];
      }
    }
}

// ---------------- 4b. V transpose: VT[b][d(1536)][T] from QKV cols 3072+ ----
__global__ void k_transpose_v(const unsigned short* __restrict__ QKV,
                              unsigned short* __restrict__ VT) {
  __shared__ unsigned short t[64 * 65];
  const int tt = blockIdx.x * 64, dt = blockIdx.y * 64, b = blockIdx.z;
  const int tid = threadIdx.x;
  const int r = tid >> 3, c0 = (tid & 7) * 8;
#pragma unroll
  for (int i = 0; i < 2; ++i) {
    int tok = r + i * 32;
    union { uint4 v; unsigned short u[8]; } vv;
    vv.v = *(const uint4*)(QKV + (size_t)(b * 1024 + tt + tok) * 4608 + 3072 + dt + c0);
#pragma unroll
    for (int j = 0; j < 8; ++j) t[tok * 65 + c0 + j] = vv.u[j];
  }
  __syncthreads();
#pragma unroll
  for (int i = 0; i < 2; ++i) {
    int d = r + i * 32;
    union { uint4 v; unsigned short u[8]; } vv;
#pragma unroll
    for (int j = 0; j < 8; ++j) vv.u[j] = t[(c0 + j) * 65 + d];
    *(uint4*)(VT + ((size_t)b * 1536 + dt + d) * 1024 + tt + c0) = vv.v;
  }
}

// ---------------- 5. causal flash attention, 128q x 128k tiles --------------
// grid (8 qtiles [reversed], 24 heads, 4 batch), block 256 = 4 waves.
// Wave: 2 q-frags (16 rows, 64 apart). No-max exp2 softmax, deferred l.
// Diagonal tile: frag0 computes keys [0,64) only; frag1 masks keys >= 64.
#define LDP 136
__global__ __launch_bounds__(256) void k_attn(const unsigned short* __restrict__ QKV,
                                              const unsigned short* __restrict__ VT,
                                              unsigned short* __restrict__ Oout) {
  __shared__ unsigned short Ks[128 * 64];     // [key][d], 8-grp XOR swizzle
  __shared__ unsigned short VTs[64 * 128];    // [d][key], 16-grp XOR swizzle
  __shared__ unsigned short Pl[4][16 * LDP];  // wave-private P staging
  const int tid = threadIdx.x;
  const int wave = tid >> 6, lane = tid & 63;
  const int qd = lane >> 4, ln = lane & 15;
  const int qb = (int)gridDim.x - 1 - (int)blockIdx.x;   // big blocks first
  const int gh = blockIdx.y, b = blockIdx.z;
  const int T = 1024, LD = 4608;
  const size_t rowbase = (size_t)b * T * LD;
  const int qcol = 64 * gh, kcol = 1536 + 64 * gh;
  const unsigned short* VTg = VT + ((size_t)b * 1536 + 64 * gh) * 1024;
  const float SCALE = 0.18033688f;  // 1/sqrt(64) * log2(e)
  const int q0 = qb * 128 + wave * 16;       // frag j adds j*64

  bf16x8 aq[2][2];
#pragma unroll
  for (int j = 0; j < 2; ++j) {
    const unsigned short* qp = QKV + rowbase + (size_t)(q0 + j * 64 + ln) * LD + qcol;
    aq[j][0] = *(const bf16x8*)(qp + qd * 8);
    aq[j][1] = *(const bf16x8*)(qp + 32 + qd * 8);
  }
  floatx4 Oacc[2][4];
#pragma unroll
  for (int j = 0; j < 2; ++j)
#pragma unroll
    for (int i = 0; i < 4; ++i) Oacc[j][i] = (floatx4){0.f, 0.f, 0.f, 0.f};
  float l_lane[2] = {0.f, 0.f};

  // K staging: wave stages rows [wave*32, +32) (4 gloads x 8 rows)
  const int rk = lane >> 3;                   // 0..7
  const int gk = ((lane & 7) ^ rk) * 8;       // swizzled source group (8-grp)
  const unsigned short* gK = QKV + rowbase + (size_t)(wave * 32 + rk) * LD + kcol + gk;
  unsigned short* lK = Ks + wave * 32 * 64;
  // VT staging: wave stages d-rows [wave*16, +16) (4 gloads x 4 rows x 128 c)
  const int rv = lane >> 4;                   // 0..3
  const int cv = lane & 15;
  unsigned short* lV = VTs + wave * 16 * 128;
  const unsigned short* gVrow[4];
  int gvcol[4];
#pragma unroll
  for (int i = 0; i < 4; ++i) {
    int d = wave * 16 + 4 * i + rv;
    gVrow[i] = VTg + (size_t)d * 1024;
    gvcol[i] = (cv ^ (4 * i + rv)) * 8;       // 16-grp swizzle by d&15
  }
  const int l7 = ln & 7;

  for (int jt = 0; jt <= qb; ++jt) {
    const int jk = jt * 128;
    const bool diag = (jt == qb);
    __syncthreads();
#pragma unroll
    for (int i = 0; i < 4; ++i) {
      gload_lds16(gK + (size_t)(jk + 8 * i) * LD, lK + i * 512);
      gload_lds16(gVrow[i] + jk + gvcol[i], lV + i * 512);
    }
    __syncthreads();

#pragma unroll
    for (int j = 0; j < 2; ++j) {
      const bool dj0 = diag && (j == 0);
      const int hmax = dj0 ? 4 : 8;
      // S^T = K Q^T : A = K[key][d] (frag h = keys h*16..+16), B = Q
      floatx4 Sc[8];
#pragma unroll
      for (int h = 0; h < 8; ++h) {
        if (h >= hmax) continue;
        Sc[h] = (floatx4){0.f, 0.f, 0.f, 0.f};
        bf16x8 a0 = *(const bf16x8*)(Ks + (h * 16 + ln) * 64 + (qd ^ l7) * 8);
        bf16x8 a1 = *(const bf16x8*)(Ks + (h * 16 + ln) * 64 + ((4 + qd) ^ l7) * 8);
        Sc[h] = __builtin_amdgcn_mfma_f32_16x16x32_bf16(a0, aq[j][0], Sc[h], 0, 0, 0);
        Sc[h] = __builtin_amdgcn_mfma_f32_16x16x32_bf16(a1, aq[j][1], Sc[h], 0, 0, 0);
      }
      const int qrow = q0 + j * 64 + ln;
      unsigned short* pw = Pl[wave];
#pragma unroll
      for (int h = 0; h < 8; ++h) {
        if (h >= hmax) continue;
        union { unsigned short u[4]; uint2 v; } pk;
#pragma unroll
        for (int r = 0; r < 4; ++r) {
          float v = fminf(Sc[h][r] * SCALE, 80.f);
          float p = __builtin_amdgcn_exp2f(v);
          if (diag && (j == 0 || h >= 4)) {
            int key = jk + h * 16 + qd * 4 + r;
            if (key > qrow) p = 0.f;
          }
          l_lane[j] += p;
          pk.u[r] = f2bf(p);
        }
        *(uint2*)(pw + ln * LDP + h * 16 + qd * 4) = pk.v;
      }
      __asm__ volatile("s_waitcnt lgkmcnt(0)" ::: "memory");
      const int smax = dj0 ? 2 : 4;
      bf16x8 pa[4];
#pragma unroll
      for (int s = 0; s < 4; ++s) {
        if (s >= smax) continue;
        pa[s] = *(const bf16x8*)(pw + ln * LDP + s * 32 + qd * 8);
      }
#pragma unroll
      for (int nc = 0; nc < 4; ++nc) {
        const int d = nc * 16 + ln;
#pragma unroll
        for (int s = 0; s < 4; ++s) {
          if (s >= smax) continue;
          bf16x8 bv = *(const bf16x8*)(VTs + d * 128 + (((s * 4 + qd) ^ ln) & 15) * 8);
          Oacc[j][nc] = __builtin_amdgcn_mfma_f32_16x16x32_bf16(pa[s], bv, Oacc[j][nc], 0, 0, 0);
        }
      }
    }
  }
  // l: sum the 4 qd-groups per ln, then normalize + store
#pragma unroll
  for (int j = 0; j < 2; ++j) {
    float l = l_lane[j];
    l += __shfl_xor(l, 16, 64);
    l += __shfl_xor(l, 32, 64);
#pragma unroll
    for (int r = 0; r < 4; ++r) {
      float inv = 1.0f / __shfl(l, qd * 4 + r, 64);
      size_t row = (size_t)b * T + q0 + j * 64 + qd * 4 + r;
#pragma unroll
      for (int nc = 0; nc < 4; ++nc)
        Oout[row * 1536 + 64 * gh + nc * 16 + ln] = f2bf(Oacc[j][nc][r] * inv);
    }
  }
}

// ---------------------------------------------------------------------------
extern "C" void kernel_launch(void* const* d_in, const int* in_sizes, int n_in,
                              void* d_out, int out_size, void* d_ws, size_t ws_size,
                              hipStream_t stream) {
  (void)in_sizes; (void)n_in; (void)out_size; (void)ws_size;
  const float* x   = (const float*)d_in[0];
  const float* WQ  = (const float*)d_in[1];
  const float* WK  = (const float*)d_in[2];
  const float* WV  = (const float*)d_in[3];
  const float* WO  = (const float*)d_in[4];
  const float* FK0 = (const float*)d_in[5];
  const float* PK0 = (const float*)d_in[6];
  const float* FV0 = (const float*)d_in[7];
  const float* PV0 = (const float*)d_in[8];
  const float* FK1 = (const float*)d_in[9];
  const float* PK1 = (const float*)d_in[10];
  const float* FV1 = (const float*)d_in[11];
  const float* PV1 = (const float*)d_in[12];

  char* ws = (char*)d_ws;
  unsigned short* X16   = (unsigned short*)(ws + 0);          // 16 MB (dead after GEMM1)
  unsigned short* VTb   = X16;                                 // VT aliases X16
  unsigned short* WTQKV = (unsigned short*)(ws + 16777216);   // 18 MB
  unsigned short* QKV   = (unsigned short*)(ws + 35651584);   // 36 MB
  unsigned short* ATT   = (unsigned short*)(ws + 73400320);   // 12 MB
  unsigned short* WTO   = (unsigned short*)(ws + 85983232);   //  6 MB

  k_prep<<<20480, 256, 0, stream>>>(x, X16, WQ, WK, WV,
                                    FK0, PK0, FV0, PV0, FK1, PK1, FV1, PV1,
                                    WTQKV, WO, WTO);
  k_gemm_bt<true, 0><<<1152, 256, 0, stream>>>(X16, WTQKV, QKV, 4096, 4608, 2048);
  k_transpose_v<<<dim3(16, 24, 4), 256, 0, stream>>>(QKV, VTb);
  k_attn<<<dim3(8, 24, 4), 256, 0, stream>>>(QKV, VTb, ATT);
  k_gemm_bt<false, 1><<<512, 256, 0, stream>>>(ATT, WTO, d_out, 4096, 2048, 1536);
}